// Round 7
// baseline (299.916 us; speedup 1.0000x reference)
//
#include <hip/hip_runtime.h>

typedef __bf16 bf16;
typedef bf16 bf16x8 __attribute__((ext_vector_type(8)));
typedef bf16 bf16x4 __attribute__((ext_vector_type(4)));
typedef bf16 bf16x2 __attribute__((ext_vector_type(2)));
typedef float f32x4 __attribute__((ext_vector_type(4)));
typedef float f32x16 __attribute__((ext_vector_type(16)));
typedef int i32x4 __attribute__((ext_vector_type(4)));

#define XSZ 4194304   // 4096*1024 elements (B*S x D)
#define WSZ 1048576   // 1024*1024
#define KDIM 1024
// 0.125 * log2(e): fold 1/sqrt(dk) AND the exp->exp2 conversion into W_q
#define QSCALE 0.1803368801111137f

// ---------- helpers ----------
__device__ __forceinline__ void async16(const bf16* g, bf16* l) {
  __builtin_amdgcn_global_load_lds(
      (const __attribute__((address_space(1))) unsigned int*)g,
      (__attribute__((address_space(3))) unsigned int*)l, 16, 0, 0);
}

__device__ __forceinline__ bf16x8 ld8(const bf16* p) {  // two aligned b64 LDS reads
  bf16x4 lo = *(const bf16x4*)p;
  bf16x4 hi = *(const bf16x4*)(p + 4);
  return __builtin_shufflevector(lo, hi, 0, 1, 2, 3, 4, 5, 6, 7);
}

__device__ __forceinline__ void st8s(bf16* p, bf16x8 v) {  // two aligned b64 LDS writes
  *(bf16x4*)p       = __builtin_shufflevector(v, v, 0, 1, 2, 3);
  *(bf16x4*)(p + 4) = __builtin_shufflevector(v, v, 4, 5, 6, 7);
}

__device__ __forceinline__ f32x4 mfma16(bf16x8 a, bf16x8 b, f32x4 c) {
  return __builtin_amdgcn_mfma_f32_16x16x32_bf16(a, b, c, 0, 0, 0);
}
__device__ __forceinline__ f32x16 mfma32(bf16x8 a, bf16x8 b, f32x16 c) {
  return __builtin_amdgcn_mfma_f32_32x32x16_bf16(a, b, c, 0, 0, 0);
}

__device__ __forceinline__ int packbf2(float lo, float hi) {
  bf16x2 t; t[0] = (bf16)lo; t[1] = (bf16)hi;
  return __builtin_bit_cast(int, t);
}

// exp2f without fast-math lowers to the accurate OCML software routine (~25 VALU
// instr) — was 62% VALUBusy in R5. v_exp_f32 is 1-ulp, plenty for bf16.
__device__ __forceinline__ float fast_exp2(float x) {
#if __has_builtin(__builtin_amdgcn_exp2f)
  return __builtin_amdgcn_exp2f(x);
#else
  return exp2f(x);
#endif
}

// ---------- fused fp32 -> bf16 cast for all 7 tensors (dsts contiguous in ws) ----------
__global__ __launch_bounds__(256) void cast_all(const float* __restrict__ Xq, const float* __restrict__ Xk,
                                                const float* __restrict__ Xv, const float* __restrict__ Wq,
                                                const float* __restrict__ Wk, const float* __restrict__ Wv,
                                                const float* __restrict__ Wo, bf16* __restrict__ dst) {
  size_t i = ((size_t)blockIdx.x * 256 + threadIdx.x) * 8;
  const float* src; size_t off; float scale = 1.0f;
  if (i < XSZ)                { src = Xq; off = i; }
  else if (i < 2 * (size_t)XSZ) { src = Xk; off = i - XSZ; }
  else if (i < 3 * (size_t)XSZ) { src = Xv; off = i - 2 * (size_t)XSZ; }
  else if (i < 3 * (size_t)XSZ + WSZ) { src = Wq; off = i - 3 * (size_t)XSZ; scale = QSCALE; }
  else if (i < 3 * (size_t)XSZ + 2 * (size_t)WSZ) { src = Wk; off = i - 3 * (size_t)XSZ - WSZ; }
  else if (i < 3 * (size_t)XSZ + 3 * (size_t)WSZ) { src = Wv; off = i - 3 * (size_t)XSZ - 2 * (size_t)WSZ; }
  else                        { src = Wo; off = i - 3 * (size_t)XSZ - 3 * (size_t)WSZ; }
  float4 a = *(const float4*)(src + off);
  float4 b = *(const float4*)(src + off + 4);
  bf16x8 o;
  o[0] = (bf16)(a.x * scale); o[1] = (bf16)(a.y * scale);
  o[2] = (bf16)(a.z * scale); o[3] = (bf16)(a.w * scale);
  o[4] = (bf16)(b.x * scale); o[5] = (bf16)(b.y * scale);
  o[6] = (bf16)(b.z * scale); o[7] = (bf16)(b.w * scale);
  *(bf16x8*)(dst + i) = o;
}

// ---------- m97-style NT GEMM core: C[128x128] += A[m,:] . B[n,:] ----------
__device__ __forceinline__ void gemm_nt_core(const bf16* __restrict__ A, const bf16* __restrict__ Bm,
                                             int m0, int n0, bf16* lds, f32x4 acc[4][4]) {
  const int t = threadIdx.x;
  const int lane = t & 63, wave = t >> 6;
  const int wm = wave & 1, wn = wave >> 1;
  const int quad = lane >> 4, m16 = lane & 15;
  bf16* As = lds;              // [128][32] row-major, no pad (global_load_lds constraint)
  bf16* Bs = lds + 128 * 32;
  const int c0 = t, c1 = t + 256;
  const bf16* ga0 = A + (size_t)(m0 + (c0 >> 2)) * KDIM + (c0 & 3) * 8;
  const bf16* ga1 = A + (size_t)(m0 + (c1 >> 2)) * KDIM + (c1 & 3) * 8;
  const bf16* gb0 = Bm + (size_t)(n0 + (c0 >> 2)) * KDIM + (c0 & 3) * 8;
  const bf16* gb1 = Bm + (size_t)(n0 + (c1 >> 2)) * KDIM + (c1 & 3) * 8;
  for (int kt = 0; kt < KDIM; kt += 32) {
    async16(ga0 + kt, As + c0 * 8);
    async16(ga1 + kt, As + c1 * 8);
    async16(gb0 + kt, Bs + c0 * 8);
    async16(gb1 + kt, Bs + c1 * 8);
    __syncthreads();
    bf16x8 af[4], bfv[4];
    #pragma unroll
    for (int i = 0; i < 4; i++)
      af[i] = *(const bf16x8*)(As + (wm * 64 + i * 16 + m16) * 32 + quad * 8);
    #pragma unroll
    for (int i = 0; i < 4; i++)
      bfv[i] = *(const bf16x8*)(Bs + (wn * 64 + i * 16 + m16) * 32 + quad * 8);
    #pragma unroll
    for (int mi = 0; mi < 4; mi++)
      #pragma unroll
      for (int ni = 0; ni < 4; ni++)
        acc[mi][ni] = mfma16(af[mi], bfv[ni], acc[mi][ni]);
    __syncthreads();
  }
}

// ---------- fused Q/K/V projection ----------
__global__ __launch_bounds__(256) void proj_gemm(const bf16* __restrict__ xq, const bf16* __restrict__ xk,
                                                 const bf16* __restrict__ xv, const bf16* __restrict__ wq,
                                                 const bf16* __restrict__ wk, const bf16* __restrict__ wv,
                                                 bf16* __restrict__ Qo, bf16* __restrict__ Ko,
                                                 bf16* __restrict__ Vo) {
  __shared__ bf16 lds[2 * 128 * 32];
  const int z = blockIdx.z;
  const bf16* A = (z == 0) ? xq : (z == 1) ? xk : xv;
  const bf16* W = (z == 0) ? wq : (z == 1) ? wk : wv;
  bf16* C = (z == 0) ? Qo : (z == 1) ? Ko : Vo;
  f32x4 acc[4][4];
  #pragma unroll
  for (int i = 0; i < 4; i++)
    #pragma unroll
    for (int j = 0; j < 4; j++) acc[i][j] = (f32x4){0.f, 0.f, 0.f, 0.f};
  gemm_nt_core(A, W, blockIdx.y * 128, blockIdx.x * 128, lds, acc);
  const int lane = threadIdx.x & 63, wave = threadIdx.x >> 6;
  const int wm = wave & 1, wn = wave >> 1, quad = lane >> 4, m16 = lane & 15;
  const int row0 = blockIdx.y * 128 + wm * 64;
  const int col0 = blockIdx.x * 128 + wn * 64;
  #pragma unroll
  for (int mi = 0; mi < 4; mi++)
    #pragma unroll
    for (int ni = 0; ni < 4; ni++)
      #pragma unroll
      for (int r = 0; r < 4; r++) {
        int row = row0 + mi * 16 + quad * 4 + r;
        int col = col0 + ni * 16 + m16;
        C[(size_t)row * 1024 + col] = (bf16)acc[mi][ni][r];
      }
}

// ---------- output projection: 128x64 tiles (512 blocks = 2/CU), fp32 out + bias ----------
__global__ __launch_bounds__(256) void out_gemm(const bf16* __restrict__ Hm, const bf16* __restrict__ wo,
                                                const float* __restrict__ bias, float* __restrict__ out) {
  __shared__ bf16 lds[128 * 32 + 64 * 32];
  bf16* As = lds;
  bf16* Bs = lds + 128 * 32;
  const int t = threadIdx.x;
  const int lane = t & 63, wave = t >> 6;
  const int wm = wave & 1, wn = wave >> 1;
  const int quad = lane >> 4, m16 = lane & 15;
  const int m0 = blockIdx.y * 128, n0 = blockIdx.x * 64;
  const int c0 = t, c1 = t + 256;
  const bf16* ga0 = Hm + (size_t)(m0 + (c0 >> 2)) * KDIM + (c0 & 3) * 8;
  const bf16* ga1 = Hm + (size_t)(m0 + (c1 >> 2)) * KDIM + (c1 & 3) * 8;
  const bf16* gb0 = wo + (size_t)(n0 + (c0 >> 2)) * KDIM + (c0 & 3) * 8;
  f32x4 acc[4][2];
  #pragma unroll
  for (int i = 0; i < 4; i++)
    #pragma unroll
    for (int j = 0; j < 2; j++) acc[i][j] = (f32x4){0.f, 0.f, 0.f, 0.f};
  for (int kt = 0; kt < KDIM; kt += 32) {
    async16(ga0 + kt, As + c0 * 8);
    async16(ga1 + kt, As + c1 * 8);
    if (c0 < 256) async16(gb0 + kt, Bs + c0 * 8);
    __syncthreads();
    bf16x8 af[4], bfv[2];
    #pragma unroll
    for (int i = 0; i < 4; i++)
      af[i] = *(const bf16x8*)(As + (wm * 64 + i * 16 + m16) * 32 + quad * 8);
    #pragma unroll
    for (int i = 0; i < 2; i++)
      bfv[i] = *(const bf16x8*)(Bs + (wn * 32 + i * 16 + m16) * 32 + quad * 8);
    #pragma unroll
    for (int mi = 0; mi < 4; mi++)
      #pragma unroll
      for (int ni = 0; ni < 2; ni++)
        acc[mi][ni] = mfma16(af[mi], bfv[ni], acc[mi][ni]);
    __syncthreads();
  }
  const int row0 = m0 + wm * 64;
  const int col0 = n0 + wn * 32;
  float bv[2];
  #pragma unroll
  for (int ni = 0; ni < 2; ni++) bv[ni] = bias[col0 + ni * 16 + m16];
  #pragma unroll
  for (int mi = 0; mi < 4; mi++)
    #pragma unroll
    for (int ni = 0; ni < 2; ni++)
      #pragma unroll
      for (int r = 0; r < 4; r++) {
        int row = row0 + mi * 16 + quad * 4 + r;
        int col = col0 + ni * 16 + m16;
        out[(size_t)row * 1024 + col] = acc[mi][ni][r] + bv[ni];
      }
}

// ---------- V transpose per head-chunk: V[2048][64] -> Vt[64][2048] ----------
__global__ __launch_bounds__(256) void transpose_v(const bf16* __restrict__ V, bf16* __restrict__ Vt) {
  __shared__ bf16 T[64 * 65];
  const int t = threadIdx.x;
  const bf16* src = V + (size_t)blockIdx.y * (2048 * 64) + (size_t)blockIdx.x * 64 * 64;
  bf16* dst = Vt + (size_t)blockIdx.y * (2048 * 64) + (size_t)blockIdx.x * 64;
  #pragma unroll
  for (int j = 0; j < 2; j++) {
    int c = t + j * 256;
    int row = c >> 3, col8 = (c & 7) * 8;
    bf16x8 v = *(const bf16x8*)(src + row * 64 + col8);
    #pragma unroll
    for (int i = 0; i < 8; i++) T[row * 65 + col8 + i] = v[i];
  }
  __syncthreads();
  #pragma unroll
  for (int j = 0; j < 2; j++) {
    int c = t + j * 256;
    int d = c >> 3, k8 = (c & 7) * 8;
    bf16x8 o;
    #pragma unroll
    for (int i = 0; i < 8; i++) o[i] = T[(k8 + i) * 65 + d];
    *(bf16x8*)(dst + (size_t)d * 2048 + k8) = o;
  }
}

// ---------- flash attention: S^T/32x32 MFMA, no-max exp2 softmax, split-K x2 ----------
// R7: TWO q-groups per wave — block covers 256 q-columns. Per staged K/V tile each
// wave issues 64 MFMAs with the same 32 LDS fragment reads (kf/vf reused across both
// groups); staging bytes and barriers per FLOP halve. Grid (8,32,2) = 512 blocks
// = exactly 2/CU. XCD-pinned swizzle keeps each (bh,slab) K/V slab in one XCD's L2.
// launch_bounds(256,2): VGPR cap 256, est ~215 -> NO SPILL (R4 lesson).
#define KS 68    // K LDS row stride: 34 dwords == 2 mod 32 -> conflict-free b64
#define VS 132   // V^T LDS row stride: 66 dwords == 2 mod 32
__global__ __launch_bounds__(256, 2) void attn_kernel(const bf16* __restrict__ Qg,
                                                      const bf16* __restrict__ Kg,
                                                      const bf16* __restrict__ Vtg,
                                                      float* __restrict__ U0,
                                                      float* __restrict__ l0) {
  __shared__ bf16 smem[128 * KS + 64 * VS];  // 34304 B
  bf16* Ks = smem;
  bf16* Vs = smem + 128 * KS;
  const int t = threadIdx.x;
  const int lane = t & 63, w = t >> 6;
  const int l31 = lane & 31, h = lane >> 5;
  // XCD-pinned swizzle: L%8 = XCD (dispatch round-robin heuristic; perf-only)
  const int L = blockIdx.x + 8 * (blockIdx.y + 32 * blockIdx.z);
  const int xcd = L & 7, j5 = L >> 3;       // j5: 0..63
  const int bh = xcd * 4 + (j5 & 3);        // 4 heads per XCD
  const int slab = (j5 >> 2) & 1;
  const int qt = j5 >> 3;                   // 0..7 (256-q tiles)
  const size_t base = (size_t)bh * (2048 * 64);
  const bf16* Kp = Kg + base + (size_t)slab * (1024 * 64);
  const bf16* Vp = Vtg + base + slab * 1024;          // V^T rows stride 2048
  float* U = U0 + (size_t)slab * (32 * 131072) + (size_t)bh * 131072;  // [64 d][2048 q]
  float* lv = l0 + slab * (32 * 2048) + bh * 2048;
  const int qc0 = qt * 256 + w * 32 + l31;            // q-group 0 column
  const int qc1 = qc0 + 128;                          // q-group 1 column

  // Q fragments (B-operand: n=l31, k=16kc+8h+j) for both groups, in regs all loop
  bf16x8 qf[2][4];
  #pragma unroll
  for (int kc = 0; kc < 4; kc++) {
    qf[0][kc] = *(const bf16x8*)(Qg + base + (size_t)qc0 * 64 + 16 * kc + 8 * h);
    qf[1][kc] = *(const bf16x8*)(Qg + base + (size_t)qc1 * 64 + 16 * kc + 8 * h);
  }

  f32x16 oacc[2][2];
  #pragma unroll
  for (int g = 0; g < 2; g++)
    #pragma unroll
    for (int mtd = 0; mtd < 2; mtd++)
      #pragma unroll
      for (int i = 0; i < 16; i++) oacc[g][mtd][i] = 0.f;
  float lrow[2] = {0.f, 0.f};

  // staging geometry (per thread, 4 chunks each for K and V)
  int krow[4], kcol[4], vrow[4], vcol[4];
  #pragma unroll
  for (int j = 0; j < 4; j++) {
    int c = t + j * 256;
    krow[j] = c >> 3;  kcol[j] = (c & 7) * 8;     // K: 128 rows x 64
    vrow[j] = c >> 4;  vcol[j] = (c & 15) * 8;    // V^T: 64 rows x 128
  }

  // preload tile 0
  bf16x8 kreg[4], vreg[4];
  #pragma unroll
  for (int j = 0; j < 4; j++) {
    kreg[j] = *(const bf16x8*)(Kp + (size_t)krow[j] * 64 + kcol[j]);
    vreg[j] = *(const bf16x8*)(Vp + (size_t)vrow[j] * 2048 + vcol[j]);
  }

  for (int kt = 0; kt < 8; kt++) {
    // write staged tile
    #pragma unroll
    for (int j = 0; j < 4; j++) st8s(Ks + krow[j] * KS + kcol[j], kreg[j]);
    #pragma unroll
    for (int j = 0; j < 4; j++) st8s(Vs + vrow[j] * VS + vcol[j], vreg[j]);
    __syncthreads();   // tile visible to all waves

    // prefetch next tile into registers (in flight during the whole compute phase)
    if (kt + 1 < 8) {
      #pragma unroll
      for (int j = 0; j < 4; j++) {
        kreg[j] = *(const bf16x8*)(Kp + (size_t)((kt + 1) * 128 + krow[j]) * 64 + kcol[j]);
        vreg[j] = *(const bf16x8*)(Vp + (size_t)vrow[j] * 2048 + (kt + 1) * 128 + vcol[j]);
      }
    }

    // per 32-key group mt: S^T for BOTH q-groups (kf reused), exp2, then PV
    #pragma unroll
    for (int mt = 0; mt < 4; mt++) {
      bf16x8 kf[4];
      #pragma unroll
      for (int kc = 0; kc < 4; kc++)
        kf[kc] = ld8(Ks + (32 * mt + l31) * KS + 16 * kc + 8 * h);
      f32x16 s0, s1;
      #pragma unroll
      for (int i = 0; i < 16; i++) { s0[i] = 0.f; s1[i] = 0.f; }
      #pragma unroll
      for (int kc = 0; kc < 4; kc++) {
        s0 = mfma32(kf[kc], qf[0][kc], s0);
        s1 = mfma32(kf[kc], qf[1][kc], s1);
      }
      int pd[2][8];
      float sum0 = 0.f, sum1 = 0.f;
      #pragma unroll
      for (int p = 0; p < 8; p++) {
        float a0 = fast_exp2(s0[2 * p]), a1 = fast_exp2(s0[2 * p + 1]);
        sum0 += a0 + a1;
        pd[0][p] = packbf2(a0, a1);
        float b0 = fast_exp2(s1[2 * p]), b1 = fast_exp2(s1[2 * p + 1]);
        sum1 += b0 + b1;
        pd[1][p] = packbf2(b0, b1);
      }
      lrow[0] += sum0; lrow[1] += sum1;
      // O^T += V^T . P^T for this group's two k-chunks (kc = 2mt, 2mt+1)
      #pragma unroll
      for (int c1 = 0; c1 < 2; c1++) {
        const int kc = 2 * mt + c1;
        bf16x8 vf0 = ld8(Vs + (size_t)l31 * VS + 16 * kc + 8 * h);
        bf16x8 vf1 = ld8(Vs + (size_t)(32 + l31) * VS + 16 * kc + 8 * h);
        const int rro = 2 * c1 + h;        // own reg-group
        const int rrp = 2 * c1 + 1 - h;    // what the partner half needs from us
        #pragma unroll
        for (int g = 0; g < 2; g++) {
          int sw0 = __shfl_xor(pd[g][2 * rrp], 32, 64);
          int sw1 = __shfl_xor(pd[g][2 * rrp + 1], 32, 64);
          int o0 = pd[g][2 * rro], o1 = pd[g][2 * rro + 1];
          i32x4 w4;
          w4.x = h ? sw0 : o0;
          w4.y = h ? sw1 : o1;
          w4.z = h ? o0 : sw0;
          w4.w = h ? o1 : sw1;
          bf16x8 pfrag = __builtin_bit_cast(bf16x8, w4);
          oacc[g][0] = mfma32(vf0, pfrag, oacc[g][0]);
          oacc[g][1] = mfma32(vf1, pfrag, oacc[g][1]);
        }
      }
    }
    __syncthreads();   // all LDS reads done before next iteration's writes
  }

  // epilogue: store U^T (coalesced: q = lane&31 contiguous) and l, both groups
  #pragma unroll
  for (int g = 0; g < 2; g++) {
    int q = g ? qc1 : qc0;
    float lr = lrow[g] + __shfl_xor(lrow[g], 32, 64);
    #pragma unroll
    for (int mtd = 0; mtd < 2; mtd++)
      #pragma unroll
      for (int r = 0; r < 16; r++) {
        int d = 32 * mtd + (r & 3) + 8 * (r >> 2) + 4 * h;
        U[(size_t)d * 2048 + q] = oacc[g][mtd][r];
      }
    if (h == 0) lv[q] = lr;
  }
}

// ---------- merge split-K partials: H[q][d] = (U0^T+U1^T)[d][q] / (l0+l1)[q] ----------
__global__ __launch_bounds__(256) void merge_kernel(const float* __restrict__ Ua,
                                                    const float* __restrict__ Ub,
                                                    const float* __restrict__ la,
                                                    const float* __restrict__ lb,
                                                    bf16* __restrict__ H) {
  __shared__ float T[64 * 65];
  const int t = threadIdx.x;
  const int q0 = blockIdx.x * 64;
  const int bh = blockIdx.y;
  const float* A = Ua + (size_t)bh * 131072;
  const float* Bp = Ub + (size_t)bh * 131072;
  #pragma unroll
  for (int p = 0; p < 4; p++) {
    int d = p * 16 + (t >> 4);
    int qq = (t & 15) * 4;
    f32x4 a = *(const f32x4*)(A + (size_t)d * 2048 + q0 + qq);
    f32x4 b = *(const f32x4*)(Bp + (size_t)d * 2048 + q0 + qq);
    #pragma unroll
    for (int i = 0; i < 4; i++) T[d * 65 + qq + i] = a[i] + b[i];
  }
  __syncthreads();
  const float* lap = la + bh * 2048 + q0;
  const float* lbp = lb + bh * 2048 + q0;
  #pragma unroll
  for (int p = 0; p < 2; p++) {
    int ql = p * 32 + (t >> 3);
    int d8 = (t & 7) * 8;
    float inv = 1.f / (lap[ql] + lbp[ql]);
    bf16x8 o;
    #pragma unroll
    for (int i = 0; i < 8; i++) o[i] = (bf16)(T[(d8 + i) * 65 + ql] * inv);
    *(bf16x8*)(H + (size_t)bh * 131072 + (size_t)(q0 + ql) * 64 + d8) = o;
  }
}

// ---------- launch ----------
extern "C" void kernel_launch(void* const* d_in, const int* in_sizes, int n_in,
                              void* d_out, int out_size, void* d_ws, size_t ws_size,
                              hipStream_t stream) {
  const float* Xq = (const float*)d_in[0];
  const float* Xk = (const float*)d_in[1];
  const float* Xv = (const float*)d_in[2];
  const float* Wq = (const float*)d_in[3];
  const float* Wk = (const float*)d_in[4];
  const float* Wv = (const float*)d_in[5];
  const float* Wo = (const float*)d_in[6];
  const float* bo = (const float*)d_in[7];

  bf16* ws = (bf16*)d_ws;
  bf16* xq = ws;                 // casts write [xq xk xv wq wk wv wo] contiguously
  bf16* xk = ws + XSZ;
  bf16* xv = ws + 2 * (size_t)XSZ;
  bf16* wq = ws + 3 * (size_t)XSZ;
  bf16* wk = wq + WSZ;
  bf16* wv = wk + WSZ;
  bf16* wo = wv + WSZ;
  bf16* q  = wo + WSZ;
  bf16* k  = q + XSZ;
  bf16* v  = k + XSZ;
  bf16* vt = xv;                 // alias: X_v dead after projection
  bf16* h  = xq;                 // alias: X_q dead after projection
  float* U0  = (float*)v;        // alias: v dead after transpose_v; U^T slabs, 33.5 MB
  float* l0f = (float*)xk;       // alias: X_k dead after projection (512 KB)

  cast_all<<<8192, 256, 0, stream>>>(Xq, Xk, Xv, Wq, Wk, Wv, Wo, ws);
  proj_gemm<<<dim3(8, 32, 3), 256, 0, stream>>>(xq, xk, xv, wq, wk, wv, q, k, v);
  transpose_v<<<dim3(32, 32), 256, 0, stream>>>(v, vt);
  attn_kernel<<<dim3(8, 32, 2), 256, 0, stream>>>(q, k, vt, U0, l0f);
  merge_kernel<<<dim3(32, 32), 256, 0, stream>>>(U0, U0 + 32 * 131072, l0f, l0f + 65536, h);
  out_gemm<<<dim3(16, 32), 256, 0, stream>>>(h, wo, bo, (float*)d_out);
}

// Round 8
// 254.351 us; speedup vs baseline: 1.1791x; 1.1791x over previous
//
#include <hip/hip_runtime.h>

typedef __bf16 bf16;
typedef bf16 bf16x8 __attribute__((ext_vector_type(8)));
typedef bf16 bf16x4 __attribute__((ext_vector_type(4)));
typedef bf16 bf16x2 __attribute__((ext_vector_type(2)));
typedef float f32x4 __attribute__((ext_vector_type(4)));
typedef float f32x16 __attribute__((ext_vector_type(16)));
typedef int i32x4 __attribute__((ext_vector_type(4)));

#define XSZ 4194304   // 4096*1024 elements (B*S x D)
#define WSZ 1048576   // 1024*1024
#define KDIM 1024
// 0.125 * log2(e): fold 1/sqrt(dk) AND the exp->exp2 conversion into W_q
#define QSCALE 0.1803368801111137f

// ---------- helpers ----------
__device__ __forceinline__ void async16(const bf16* g, bf16* l) {
  __builtin_amdgcn_global_load_lds(
      (const __attribute__((address_space(1))) unsigned int*)g,
      (__attribute__((address_space(3))) unsigned int*)l, 16, 0, 0);
}

__device__ __forceinline__ bf16x8 ld8(const bf16* p) {  // two aligned b64 LDS reads
  bf16x4 lo = *(const bf16x4*)p;
  bf16x4 hi = *(const bf16x4*)(p + 4);
  return __builtin_shufflevector(lo, hi, 0, 1, 2, 3, 4, 5, 6, 7);
}

__device__ __forceinline__ void st8s(bf16* p, bf16x8 v) {  // two aligned b64 LDS writes
  *(bf16x4*)p       = __builtin_shufflevector(v, v, 0, 1, 2, 3);
  *(bf16x4*)(p + 4) = __builtin_shufflevector(v, v, 4, 5, 6, 7);
}

__device__ __forceinline__ f32x4 mfma16(bf16x8 a, bf16x8 b, f32x4 c) {
  return __builtin_amdgcn_mfma_f32_16x16x32_bf16(a, b, c, 0, 0, 0);
}
__device__ __forceinline__ f32x16 mfma32(bf16x8 a, bf16x8 b, f32x16 c) {
  return __builtin_amdgcn_mfma_f32_32x32x16_bf16(a, b, c, 0, 0, 0);
}

__device__ __forceinline__ int packbf2(float lo, float hi) {
  bf16x2 t; t[0] = (bf16)lo; t[1] = (bf16)hi;
  return __builtin_bit_cast(int, t);
}

// exp2f without fast-math lowers to the accurate OCML software routine (~25 VALU
// instr) — was 62% VALUBusy in R5. v_exp_f32 is 1-ulp, plenty for bf16.
__device__ __forceinline__ float fast_exp2(float x) {
#if __has_builtin(__builtin_amdgcn_exp2f)
  return __builtin_amdgcn_exp2f(x);
#else
  return exp2f(x);
#endif
}

// ---------- fused fp32 -> bf16 cast for all 7 tensors (dsts contiguous in ws) ----------
__global__ __launch_bounds__(256) void cast_all(const float* __restrict__ Xq, const float* __restrict__ Xk,
                                                const float* __restrict__ Xv, const float* __restrict__ Wq,
                                                const float* __restrict__ Wk, const float* __restrict__ Wv,
                                                const float* __restrict__ Wo, bf16* __restrict__ dst) {
  size_t i = ((size_t)blockIdx.x * 256 + threadIdx.x) * 8;
  const float* src; size_t off; float scale = 1.0f;
  if (i < XSZ)                { src = Xq; off = i; }
  else if (i < 2 * (size_t)XSZ) { src = Xk; off = i - XSZ; }
  else if (i < 3 * (size_t)XSZ) { src = Xv; off = i - 2 * (size_t)XSZ; }
  else if (i < 3 * (size_t)XSZ + WSZ) { src = Wq; off = i - 3 * (size_t)XSZ; scale = QSCALE; }
  else if (i < 3 * (size_t)XSZ + 2 * (size_t)WSZ) { src = Wk; off = i - 3 * (size_t)XSZ - WSZ; }
  else if (i < 3 * (size_t)XSZ + 3 * (size_t)WSZ) { src = Wv; off = i - 3 * (size_t)XSZ - 2 * (size_t)WSZ; }
  else                        { src = Wo; off = i - 3 * (size_t)XSZ - 3 * (size_t)WSZ; }
  float4 a = *(const float4*)(src + off);
  float4 b = *(const float4*)(src + off + 4);
  bf16x8 o;
  o[0] = (bf16)(a.x * scale); o[1] = (bf16)(a.y * scale);
  o[2] = (bf16)(a.z * scale); o[3] = (bf16)(a.w * scale);
  o[4] = (bf16)(b.x * scale); o[5] = (bf16)(b.y * scale);
  o[6] = (bf16)(b.z * scale); o[7] = (bf16)(b.w * scale);
  *(bf16x8*)(dst + i) = o;
}

// ---------- m97-style NT GEMM core: C[128x128] += A[m,:] . B[n,:] ----------
__device__ __forceinline__ void gemm_nt_core(const bf16* __restrict__ A, const bf16* __restrict__ Bm,
                                             int m0, int n0, bf16* lds, f32x4 acc[4][4]) {
  const int t = threadIdx.x;
  const int lane = t & 63, wave = t >> 6;
  const int wm = wave & 1, wn = wave >> 1;
  const int quad = lane >> 4, m16 = lane & 15;
  bf16* As = lds;              // [128][32] row-major, no pad (global_load_lds constraint)
  bf16* Bs = lds + 128 * 32;
  const int c0 = t, c1 = t + 256;
  const bf16* ga0 = A + (size_t)(m0 + (c0 >> 2)) * KDIM + (c0 & 3) * 8;
  const bf16* ga1 = A + (size_t)(m0 + (c1 >> 2)) * KDIM + (c1 & 3) * 8;
  const bf16* gb0 = Bm + (size_t)(n0 + (c0 >> 2)) * KDIM + (c0 & 3) * 8;
  const bf16* gb1 = Bm + (size_t)(n0 + (c1 >> 2)) * KDIM + (c1 & 3) * 8;
  for (int kt = 0; kt < KDIM; kt += 32) {
    async16(ga0 + kt, As + c0 * 8);
    async16(ga1 + kt, As + c1 * 8);
    async16(gb0 + kt, Bs + c0 * 8);
    async16(gb1 + kt, Bs + c1 * 8);
    __syncthreads();
    bf16x8 af[4], bfv[4];
    #pragma unroll
    for (int i = 0; i < 4; i++)
      af[i] = *(const bf16x8*)(As + (wm * 64 + i * 16 + m16) * 32 + quad * 8);
    #pragma unroll
    for (int i = 0; i < 4; i++)
      bfv[i] = *(const bf16x8*)(Bs + (wn * 64 + i * 16 + m16) * 32 + quad * 8);
    #pragma unroll
    for (int mi = 0; mi < 4; mi++)
      #pragma unroll
      for (int ni = 0; ni < 4; ni++)
        acc[mi][ni] = mfma16(af[mi], bfv[ni], acc[mi][ni]);
    __syncthreads();
  }
}

// ---------- fused Q/K/V projection ----------
__global__ __launch_bounds__(256) void proj_gemm(const bf16* __restrict__ xq, const bf16* __restrict__ xk,
                                                 const bf16* __restrict__ xv, const bf16* __restrict__ wq,
                                                 const bf16* __restrict__ wk, const bf16* __restrict__ wv,
                                                 bf16* __restrict__ Qo, bf16* __restrict__ Ko,
                                                 bf16* __restrict__ Vo) {
  __shared__ bf16 lds[2 * 128 * 32];
  const int z = blockIdx.z;
  const bf16* A = (z == 0) ? xq : (z == 1) ? xk : xv;
  const bf16* W = (z == 0) ? wq : (z == 1) ? wk : wv;
  bf16* C = (z == 0) ? Qo : (z == 1) ? Ko : Vo;
  f32x4 acc[4][4];
  #pragma unroll
  for (int i = 0; i < 4; i++)
    #pragma unroll
    for (int j = 0; j < 4; j++) acc[i][j] = (f32x4){0.f, 0.f, 0.f, 0.f};
  gemm_nt_core(A, W, blockIdx.y * 128, blockIdx.x * 128, lds, acc);
  const int lane = threadIdx.x & 63, wave = threadIdx.x >> 6;
  const int wm = wave & 1, wn = wave >> 1, quad = lane >> 4, m16 = lane & 15;
  const int row0 = blockIdx.y * 128 + wm * 64;
  const int col0 = blockIdx.x * 128 + wn * 64;
  #pragma unroll
  for (int mi = 0; mi < 4; mi++)
    #pragma unroll
    for (int ni = 0; ni < 4; ni++)
      #pragma unroll
      for (int r = 0; r < 4; r++) {
        int row = row0 + mi * 16 + quad * 4 + r;
        int col = col0 + ni * 16 + m16;
        C[(size_t)row * 1024 + col] = (bf16)acc[mi][ni][r];
      }
}

// ---------- output projection: 128x64 tiles (512 blocks = 2/CU), fp32 out + bias ----------
__global__ __launch_bounds__(256) void out_gemm(const bf16* __restrict__ Hm, const bf16* __restrict__ wo,
                                                const float* __restrict__ bias, float* __restrict__ out) {
  __shared__ bf16 lds[128 * 32 + 64 * 32];
  bf16* As = lds;
  bf16* Bs = lds + 128 * 32;
  const int t = threadIdx.x;
  const int lane = t & 63, wave = t >> 6;
  const int wm = wave & 1, wn = wave >> 1;
  const int quad = lane >> 4, m16 = lane & 15;
  const int m0 = blockIdx.y * 128, n0 = blockIdx.x * 64;
  const int c0 = t, c1 = t + 256;
  const bf16* ga0 = Hm + (size_t)(m0 + (c0 >> 2)) * KDIM + (c0 & 3) * 8;
  const bf16* ga1 = Hm + (size_t)(m0 + (c1 >> 2)) * KDIM + (c1 & 3) * 8;
  const bf16* gb0 = wo + (size_t)(n0 + (c0 >> 2)) * KDIM + (c0 & 3) * 8;
  f32x4 acc[4][2];
  #pragma unroll
  for (int i = 0; i < 4; i++)
    #pragma unroll
    for (int j = 0; j < 2; j++) acc[i][j] = (f32x4){0.f, 0.f, 0.f, 0.f};
  for (int kt = 0; kt < KDIM; kt += 32) {
    async16(ga0 + kt, As + c0 * 8);
    async16(ga1 + kt, As + c1 * 8);
    if (c0 < 256) async16(gb0 + kt, Bs + c0 * 8);
    __syncthreads();
    bf16x8 af[4], bfv[2];
    #pragma unroll
    for (int i = 0; i < 4; i++)
      af[i] = *(const bf16x8*)(As + (wm * 64 + i * 16 + m16) * 32 + quad * 8);
    #pragma unroll
    for (int i = 0; i < 2; i++)
      bfv[i] = *(const bf16x8*)(Bs + (wn * 32 + i * 16 + m16) * 32 + quad * 8);
    #pragma unroll
    for (int mi = 0; mi < 4; mi++)
      #pragma unroll
      for (int ni = 0; ni < 2; ni++)
        acc[mi][ni] = mfma16(af[mi], bfv[ni], acc[mi][ni]);
    __syncthreads();
  }
  const int row0 = m0 + wm * 64;
  const int col0 = n0 + wn * 32;
  float bv[2];
  #pragma unroll
  for (int ni = 0; ni < 2; ni++) bv[ni] = bias[col0 + ni * 16 + m16];
  #pragma unroll
  for (int mi = 0; mi < 4; mi++)
    #pragma unroll
    for (int ni = 0; ni < 2; ni++)
      #pragma unroll
      for (int r = 0; r < 4; r++) {
        int row = row0 + mi * 16 + quad * 4 + r;
        int col = col0 + ni * 16 + m16;
        out[(size_t)row * 1024 + col] = acc[mi][ni][r] + bv[ni];
      }
}

// ---------- V transpose per head-chunk: V[2048][64] -> Vt[64][2048] ----------
__global__ __launch_bounds__(256) void transpose_v(const bf16* __restrict__ V, bf16* __restrict__ Vt) {
  __shared__ bf16 T[64 * 65];
  const int t = threadIdx.x;
  const bf16* src = V + (size_t)blockIdx.y * (2048 * 64) + (size_t)blockIdx.x * 64 * 64;
  bf16* dst = Vt + (size_t)blockIdx.y * (2048 * 64) + (size_t)blockIdx.x * 64;
  #pragma unroll
  for (int j = 0; j < 2; j++) {
    int c = t + j * 256;
    int row = c >> 3, col8 = (c & 7) * 8;
    bf16x8 v = *(const bf16x8*)(src + row * 64 + col8);
    #pragma unroll
    for (int i = 0; i < 8; i++) T[row * 65 + col8 + i] = v[i];
  }
  __syncthreads();
  #pragma unroll
  for (int j = 0; j < 2; j++) {
    int c = t + j * 256;
    int d = c >> 3, k8 = (c & 7) * 8;
    bf16x8 o;
    #pragma unroll
    for (int i = 0; i < 8; i++) o[i] = T[(k8 + i) * 65 + d];
    *(bf16x8*)(dst + (size_t)d * 2048 + k8) = o;
  }
}

// ---------- flash attention: S^T/32x32 MFMA, no-max exp2 softmax, FULL-SEQ ----------
// R8: back to R6's proven register budget (1 q-group, VGPR ~84), but each block
// walks all 2048 keys (16 tiles) -> NO split-K: merge kernel gone, U fp32 (67 MB)
// replaced by direct bf16 H store (8 MB) via LDS-transpose epilogue. Grid (16,32)
// = 512 blocks = 2/CU; XCD-pinned swizzle -> 4 bh per XCD = 2 MB K+V per L2.
#define KS 68    // K LDS row stride: 34 dwords == 2 mod 32 -> conflict-free b64
#define VS 132   // V^T LDS row stride: 66 dwords == 2 mod 32
__global__ __launch_bounds__(256, 3) void attn_kernel(const bf16* __restrict__ Qg,
                                                      const bf16* __restrict__ Kg,
                                                      const bf16* __restrict__ Vtg,
                                                      bf16* __restrict__ Hout) {
  __shared__ bf16 smem[128 * KS + 64 * VS];  // 34304 B
  bf16* Ks = smem;
  bf16* Vs = smem + 128 * KS;
  const int t = threadIdx.x;
  const int lane = t & 63, w = t >> 6;
  const int l31 = lane & 31, h = lane >> 5;
  // XCD-pinned swizzle: L%8 = XCD (dispatch round-robin heuristic; perf-only)
  const int L = blockIdx.x + 16 * blockIdx.y;   // 0..511
  const int xcd = L & 7, j5 = L >> 3;           // j5: 0..63
  const int bh = xcd * 4 + (j5 & 3);            // 4 heads per XCD
  const int qt = j5 >> 2;                       // 0..15
  const size_t base = (size_t)bh * (2048 * 64);
  const bf16* Kp = Kg + base;
  const bf16* Vp = Vtg + base;                  // V^T rows stride 2048
  const int q = qt * 128 + w * 32 + l31;        // this lane's q-column

  // Q fragments (B-operand: n=l31, k=16kc+8h+j) in registers for the whole loop
  bf16x8 qf[4];
  #pragma unroll
  for (int kc = 0; kc < 4; kc++)
    qf[kc] = *(const bf16x8*)(Qg + base + (size_t)q * 64 + 16 * kc + 8 * h);

  f32x16 oacc[2];
  #pragma unroll
  for (int mt = 0; mt < 2; mt++)
    #pragma unroll
    for (int i = 0; i < 16; i++) oacc[mt][i] = 0.f;
  float lrow = 0.f;

  // staging geometry (per thread, 4 chunks each for K and V)
  int krow[4], kcol[4], vrow[4], vcol[4];
  #pragma unroll
  for (int j = 0; j < 4; j++) {
    int c = t + j * 256;
    krow[j] = c >> 3;  kcol[j] = (c & 7) * 8;     // K: 128 rows x 64
    vrow[j] = c >> 4;  vcol[j] = (c & 15) * 8;    // V^T: 64 rows x 128
  }

  // preload tile 0
  bf16x8 kreg[4], vreg[4];
  #pragma unroll
  for (int j = 0; j < 4; j++) {
    kreg[j] = *(const bf16x8*)(Kp + (size_t)krow[j] * 64 + kcol[j]);
    vreg[j] = *(const bf16x8*)(Vp + (size_t)vrow[j] * 2048 + vcol[j]);
  }

  for (int kt = 0; kt < 16; kt++) {
    // write staged tile
    #pragma unroll
    for (int j = 0; j < 4; j++) st8s(Ks + krow[j] * KS + kcol[j], kreg[j]);
    #pragma unroll
    for (int j = 0; j < 4; j++) st8s(Vs + vrow[j] * VS + vcol[j], vreg[j]);
    __syncthreads();   // tile visible to all waves

    // prefetch next tile into registers (in flight during the whole compute phase)
    if (kt + 1 < 16) {
      #pragma unroll
      for (int j = 0; j < 4; j++) {
        kreg[j] = *(const bf16x8*)(Kp + (size_t)((kt + 1) * 128 + krow[j]) * 64 + kcol[j]);
        vreg[j] = *(const bf16x8*)(Vp + (size_t)vrow[j] * 2048 + (kt + 1) * 128 + vcol[j]);
      }
    }

    // per 32-key group: S^T = K.Q^T -> exp2 -> pack -> PV immediately (pd = 8 regs)
    #pragma unroll
    for (int mt = 0; mt < 4; mt++) {
      f32x16 sacc;
      #pragma unroll
      for (int i = 0; i < 16; i++) sacc[i] = 0.f;
      #pragma unroll
      for (int kc = 0; kc < 4; kc++) {
        bf16x8 kf = ld8(Ks + (32 * mt + l31) * KS + 16 * kc + 8 * h);
        sacc = mfma32(kf, qf[kc], sacc);
      }
      int pd[8];
      float sum = 0.f;
      #pragma unroll
      for (int p = 0; p < 8; p++) {
        float p0 = fast_exp2(sacc[2 * p]);
        float p1 = fast_exp2(sacc[2 * p + 1]);
        sum += p0 + p1;
        pd[p] = packbf2(p0, p1);
      }
      lrow += sum;
      // O^T += V^T . P^T for this group's two k-chunks (kc = 2mt, 2mt+1)
      #pragma unroll
      for (int c1 = 0; c1 < 2; c1++) {
        const int kc = 2 * mt + c1;
        const int rro = 2 * c1 + h;        // own reg-group
        const int rrp = 2 * c1 + 1 - h;    // what the partner half needs from us
        int s0 = __shfl_xor(pd[2 * rrp], 32, 64);
        int s1 = __shfl_xor(pd[2 * rrp + 1], 32, 64);
        int o0 = pd[2 * rro], o1 = pd[2 * rro + 1];
        i32x4 w4;
        w4.x = h ? s0 : o0;
        w4.y = h ? s1 : o1;
        w4.z = h ? o0 : s0;
        w4.w = h ? o1 : s1;
        bf16x8 pfrag = __builtin_bit_cast(bf16x8, w4);
        #pragma unroll
        for (int mtd = 0; mtd < 2; mtd++) {
          bf16x8 vf = ld8(Vs + (32 * mtd + l31) * VS + 16 * kc + 8 * h);
          oacc[mtd] = mfma32(vf, pfrag, oacc[mtd]);
        }
      }
    }
    __syncthreads();   // all LDS reads done before next iteration's writes
  }

  // epilogue: normalize, transpose O^T -> O[q][d] through LDS, store bf16 H.
  // Per-wave private 8 KB region of smem (loop's final barrier freed it).
  lrow += __shfl_xor(lrow, 32, 64);
  float inv = 1.f / lrow;
  float* Tf = (float*)smem + w * 2048;   // [64 d][32 q] per wave
  #pragma unroll
  for (int mt = 0; mt < 2; mt++)
    #pragma unroll
    for (int r = 0; r < 16; r++) {
      int d = 32 * mt + (r & 3) + 8 * (r >> 2) + 4 * h;
      Tf[d * 32 + l31] = oacc[mt][r] * inv;   // lanes l31 stride-1, h rows: 2-way max
    }
  __syncthreads();   // cross-lane LDS dependency (cheap, once per kernel)
  bf16* Hq = Hout + base + (size_t)(qt * 128 + w * 32 + l31) * 64 + 32 * h;
  #pragma unroll
  for (int s = 0; s < 4; s++) {
    bf16x8 o;
    #pragma unroll
    for (int i = 0; i < 8; i++) o[i] = (bf16)Tf[(32 * h + s * 8 + i) * 32 + l31];
    *(bf16x8*)(Hq + s * 8) = o;
  }
}

// ---------- launch ----------
extern "C" void kernel_launch(void* const* d_in, const int* in_sizes, int n_in,
                              void* d_out, int out_size, void* d_ws, size_t ws_size,
                              hipStream_t stream) {
  const float* Xq = (const float*)d_in[0];
  const float* Xk = (const float*)d_in[1];
  const float* Xv = (const float*)d_in[2];
  const float* Wq = (const float*)d_in[3];
  const float* Wk = (const float*)d_in[4];
  const float* Wv = (const float*)d_in[5];
  const float* Wo = (const float*)d_in[6];
  const float* bo = (const float*)d_in[7];

  bf16* ws = (bf16*)d_ws;
  bf16* xq = ws;                 // casts write [xq xk xv wq wk wv wo] contiguously
  bf16* xk = ws + XSZ;
  bf16* xv = ws + 2 * (size_t)XSZ;
  bf16* wq = ws + 3 * (size_t)XSZ;
  bf16* wk = wq + WSZ;
  bf16* wv = wk + WSZ;
  bf16* wo = wv + WSZ;
  bf16* q  = wo + WSZ;
  bf16* k  = q + XSZ;
  bf16* v  = k + XSZ;
  bf16* vt = xv;                 // alias: X_v dead after projection
  bf16* h  = xq;                 // alias: X_q dead after projection

  cast_all<<<8192, 256, 0, stream>>>(Xq, Xk, Xv, Wq, Wk, Wv, Wo, ws);
  proj_gemm<<<dim3(8, 32, 3), 256, 0, stream>>>(xq, xk, xv, wq, wk, wv, q, k, v);
  transpose_v<<<dim3(32, 32), 256, 0, stream>>>(v, vt);
  attn_kernel<<<dim3(16, 32), 256, 0, stream>>>(q, k, vt, h);
  out_gemm<<<dim3(16, 32), 256, 0, stream>>>(h, wo, bo, (float*)d_out);
}